// Round 9
// baseline (494.888 us; speedup 1.0000x reference)
//
#include <hip/hip_runtime.h>
#include <cstdint>

#define NN 16000
#define KK 16
#define FIN 32
#define HH 64
#define NE (NN*KK)
#define GG 64
#define NCELL (GG*GG)

// ---------------------------------------------------------------- prep + count
__global__ __launch_bounds__(256) void prep_count_kernel(const float* __restrict__ c,
                                                         float4* __restrict__ pack,
                                                         unsigned* __restrict__ cellid,
                                                         unsigned* __restrict__ cnt,
                                                         unsigned* __restrict__ gmm) {
#pragma clang fp contract(off)
  int i = blockIdx.x * 256 + threadIdx.x;
  if (i == 0) { gmm[0] = 0x7F800000u; gmm[1] = 0u; }  // min=+inf bits, max=0 (d>=0)
  if (i >= NN) return;
  float xv = c[2*i], yv = c[2*i+1];
  float xx = xv * xv;            // round(x^2)  (no fma: contract off)
  float yy = yv * yv;            // round(y^2)
  float sq = xx + yy;            // round(xx+yy)
  pack[i] = make_float4(xv, yv, sq, __uint_as_float((unsigned)i));
  int cx = (int)(xv * GG); cx = cx > GG-1 ? GG-1 : (cx < 0 ? 0 : cx);
  int cy = (int)(yv * GG); cy = cy > GG-1 ? GG-1 : (cy < 0 ? 0 : cy);
  unsigned cell = (unsigned)(cy * GG + cx);
  cellid[i] = cell;
  atomicAdd(&cnt[cell], 1u);
}

// ---------------------------------------------------------------- prefix scan (single block, wave-shuffle)
__global__ __launch_bounds__(1024) void scan_kernel(const unsigned* __restrict__ cnt,
                                                    unsigned* __restrict__ cstart,
                                                    unsigned* __restrict__ cursor) {
  __shared__ unsigned wsum[16];
  int tid = threadIdx.x;
  int lane = tid & 63, wv = tid >> 6;
  unsigned c0 = cnt[tid*4+0], c1 = cnt[tid*4+1], c2 = cnt[tid*4+2], c3 = cnt[tid*4+3];
  unsigned s = c0 + c1 + c2 + c3;
  unsigned v = s;
#pragma unroll
  for (int off = 1; off < 64; off <<= 1) {
    unsigned u = __shfl_up(v, off, 64);
    if (lane >= off) v += u;
  }
  if (lane == 63) wsum[wv] = v;
  __syncthreads();
  if (wv == 0) {
    unsigned t = (lane < 16) ? wsum[lane] : 0u;
    unsigned vv = t;
#pragma unroll
    for (int off = 1; off < 16; off <<= 1) {
      unsigned u = __shfl_up(vv, off, 64);
      if (lane >= off) vv += u;
    }
    if (lane < 16) wsum[lane] = vv - t;            // exclusive
  }
  __syncthreads();
  unsigned b = wsum[wv] + v - s;
  cstart[tid*4+0] = b; cursor[tid*4+0] = b; b += c0;
  cstart[tid*4+1] = b; cursor[tid*4+1] = b; b += c1;
  cstart[tid*4+2] = b; cursor[tid*4+2] = b; b += c2;
  cstart[tid*4+3] = b; cursor[tid*4+3] = b; b += c3;
  if (tid == 1023) cstart[NCELL] = b;              // == NN
}

// ---------------------------------------------------------------- scatter into cell order
__global__ __launch_bounds__(256) void scatter_kernel(const float4* __restrict__ pack,
                                                      const unsigned* __restrict__ cellid,
                                                      unsigned* __restrict__ cursor,
                                                      float4* __restrict__ sorted,
                                                      int* __restrict__ sid) {
  int i = blockIdx.x * 256 + threadIdx.x;
  if (i >= NN) return;
  unsigned p = atomicAdd(&cursor[cellid[i]], 1u);
  sorted[p] = pack[i];                             // .w carries original index bits
  sid[p] = i;
}

// ---------------------------------------------------------------- knn: one 64-lane wave per node
// d2 bit-exact vs passing rounds: dot = fma(y_i,y_j, round(x_i*x_j));
// d2 = round((sq_i+sq_j) - 2*dot). Key = map(d2bits)<<32 | j (index tie-break).
// Lanes stride each cell-row span; per-lane sorted top-16 lists.
// Stop test (exact): count of scanned keys with high32 <= map(edge^2 - 1e-5)
// summed over the wave >= 16. Outside-rect candidates have computed d2 >
// edge^2 - 1e-6 > lim (noise margin 9e-6 >> f32 rounding here), so the
// scanned set provably contains the true top-16. Merge: 16-round wave-min
// extraction (keys unique). Edge epilogue identical ops to passing rounds.
__global__ __launch_bounds__(256) void knn_kernel(const float4* __restrict__ sorted,
                                                  const unsigned* __restrict__ cstart,
                                                  const float* __restrict__ c,
                                                  int* __restrict__ nbr,
                                                  float* __restrict__ de,
                                                  unsigned* __restrict__ gmm) {
#pragma clang fp contract(off)
  const int t = (blockIdx.x << 2) + (threadIdx.x >> 6);   // sorted node index
  const int lane = threadIdx.x & 63;
  const float4 me = sorted[t];
  const int myid = (int)__float_as_uint(me.w);
  const float h = 1.0f / GG;                       // exact 2^-6
  int cx = (int)(me.x * GG); cx = cx > GG-1 ? GG-1 : (cx < 0 ? 0 : cx);
  int cy = (int)(me.y * GG); cy = cy > GG-1 ? GG-1 : (cy < 0 ? 0 : cy);

  unsigned long long kd[KK];
#pragma unroll
  for (int m = 0; m < KK; ++m) kd[m] = ~0ull;

  auto process = [&](float4 cand) {
    int j = (int)__float_as_uint(cand.w);
    float xprod = me.x * cand.x;                       // round(x_i*x_j)
    float dot   = __builtin_fmaf(me.y, cand.y, xprod); // BLAS K=2 fma
    float S     = me.z + cand.z;                       // round(sq_i+sq_j)
    float twod  = dot + dot;                           // exact *2
    float d2    = S - twod;                            // one rounding
    unsigned ub = __float_as_uint(d2);
    ub = (ub & 0x80000000u) ? ~ub : (ub | 0x80000000u);
    unsigned long long key = ((unsigned long long)ub << 32) | (unsigned)j;
    if (j != myid && key < kd[KK-1]) {
      unsigned long long ck = key;
#pragma unroll
      for (int m = 0; m < KK; ++m) {
        bool sw = ck < kd[m];
        unsigned long long lo = sw ? ck : kd[m];
        unsigned long long hi = sw ? kd[m] : ck;
        kd[m] = lo; ck = hi;
      }
    }
  };
  auto scanRow = [&](int y, int x0, int x1) {
    if (y < 0 || y >= GG) return;
    x0 = x0 < 0 ? 0 : x0;
    x1 = x1 > GG-1 ? GG-1 : x1;
    if (x0 > x1) return;
    unsigned p0 = cstart[y*GG + x0];
    unsigned p1 = cstart[y*GG + x1 + 1];
    for (unsigned p = p0 + (unsigned)lane; p < p1; p += 64) process(sorted[p]);
  };

  int R = 2;
  int lxa = cx-2 < 0 ? 0 : cx-2;
  int lxb = cx+2 > GG-1 ? GG-1 : cx+2;
  int lya = cy-2 < 0 ? 0 : cy-2;
  int lyb = cy+2 > GG-1 ? GG-1 : cy+2;
  for (int y = lya; y <= lyb; ++y) scanRow(y, lxa, lxb);

  while (true) {
    bool whole = (lxa <= 0) && (lxb >= GG-1) && (lya <= 0) && (lyb >= GG-1);
    if (whole) break;
    float edge = 1e30f;
    if (lxa > 0)    edge = fminf(edge, me.x - (float)lxa * h);
    if (lxb < GG-1) edge = fminf(edge, (float)(lxb+1) * h - me.x);
    if (lya > 0)    edge = fminf(edge, me.y - (float)lya * h);
    if (lyb < GG-1) edge = fminf(edge, (float)(lyb+1) * h - me.y);
    float lim = edge * edge - 1e-5f;                 // margin >> Gram noise (~1e-6)
    bool done = false;
    if (lim > 0.0f) {
      unsigned lb = __float_as_uint(lim) | 0x80000000u;   // map(lim), lim>0
      int cle = 0;
#pragma unroll
      for (int m = 0; m < KK; ++m) cle += ((unsigned)(kd[m] >> 32) <= lb) ? 1 : 0;
#pragma unroll
      for (int off = 32; off > 0; off >>= 1) cle += __shfl_xor(cle, off, 64);
      done = cle >= KK;
    }
    if (done) break;
    ++R;
    int nxa = cx-R < 0 ? 0 : cx-R;
    int nxb = cx+R > GG-1 ? GG-1 : cx+R;
    int nya = cy-R < 0 ? 0 : cy-R;
    int nyb = cy+R > GG-1 ? GG-1 : cy+R;
    if (nya < lya) scanRow(nya, nxa, nxb);
    if (nyb > lyb) scanRow(nyb, nxa, nxb);
    if (nxa < lxa) for (int y = lya; y <= lyb; ++y) scanRow(y, nxa, nxa);
    if (nxb > lxb) for (int y = lya; y <= lyb; ++y) scanRow(y, nxb, nxb);
    lxa = nxa; lxb = nxb; lya = nya; lyb = nyb;
  }

  // ---- merge: 16-round wave-wide min extraction (keys unique via j bits)
  unsigned res = 0;
  for (int r = 0; r < KK; ++r) {
    unsigned long long md = kd[0];
#pragma unroll
    for (int off = 32; off > 0; off >>= 1) {
      unsigned long long od = __shfl_xor(md, off, 64);
      md = od < md ? od : md;
    }
    if (kd[0] == md) {                              // unique winner lane pops
#pragma unroll
      for (int m = 0; m < KK-1; ++m) kd[m] = kd[m+1];
      kd[KK-1] = ~0ull;
    }
    if (lane == r) res = (unsigned)(md & 0xFFFFFFFFull);
  }

  // ---- write nbr + edge epilogue (identical ops to passing rounds)
  unsigned bmin = 0xFFFFFFFFu, bmax = 0u;
  if (lane < KK) {
    int j = (int)res;
    nbr[myid*KK + lane] = j;
    float dx = me.x - c[2*j];
    float dy = me.y - c[2*j+1];
    float xx = dx * dx;
    float yy = dy * dy;
    float d  = __builtin_sqrtf(xx + yy);
    de[myid*KK + lane] = d;
    unsigned bb = __float_as_uint(d);               // d >= 0: bit order == float order
    bmin = bb; bmax = bb;
  }
#pragma unroll
  for (int off = 32; off > 0; off >>= 1) {
    unsigned ob = __shfl_xor(bmin, off, 64);
    bmin = bmin < ob ? bmin : ob;
    unsigned oB = __shfl_xor(bmax, off, 64);
    bmax = bmax > oB ? bmax : oB;
  }
  if (lane == 0) {
    atomicMin(&gmm[0], bmin);
    atomicMax(&gmm[1], bmax);
  }
}

// ---------------------------------------------------------------- ew + deg + dis
__global__ __launch_bounds__(256) void ewdeg_kernel(const unsigned* __restrict__ gmm,
                                                    float* __restrict__ de,   // in: d, out: ew
                                                    float* __restrict__ dis) {
#pragma clang fp contract(off)
  int i = blockIdx.x * 256 + threadIdx.x;
  if (i >= NN) return;
  float mx  = __uint_as_float(gmm[1]);
  float rng = mx - __uint_as_float(gmm[0]);
  float deg = 0.0f;                         // edges first, self-loop last (segment_sum order)
  float4* dp = (float4*)(de + i*KK);
#pragma unroll
  for (int qq = 0; qq < 4; ++qq) {
    float4 v = dp[qq];
    float e0 = (mx - v.x) / rng;
    float e1 = (mx - v.y) / rng;
    float e2 = (mx - v.z) / rng;
    float e3 = (mx - v.w) / rng;
    deg = deg + e0; deg = deg + e1;
    deg = deg + e2; deg = deg + e3;
    dp[qq] = make_float4(e0, e1, e2, e3);
  }
  deg = deg + 1.0f;                         // self-loop weight 1, added last
  dis[i] = 1.0f / __builtin_sqrtf(deg);     // deg >= 1
}

// ---------------------------------------------------------------- gemm1: xw1 = x @ W1, KIN=32, 4 features/thread
__global__ __launch_bounds__(256) void gemm1_kernel(const float* __restrict__ a,
                                                    const float* __restrict__ w,
                                                    float* __restrict__ o) {
  int gid = blockIdx.x * 256 + threadIdx.x;   // N*16 total
  int i = gid >> 4, fq = gid & 15;
  const float4* ar = (const float4*)(a + i * FIN);
  float4 A[FIN/4];
#pragma unroll
  for (int qq = 0; qq < FIN/4; ++qq) A[qq] = ar[qq];
  float4 acc = make_float4(0.f, 0.f, 0.f, 0.f);
#pragma unroll
  for (int k = 0; k < FIN; ++k) {
    float av = ((const float*)A)[k];
    float4 wv4 = *(const float4*)(w + k*HH + 4*fq);
    acc.x = fmaf(av, wv4.x, acc.x);
    acc.y = fmaf(av, wv4.y, acc.y);
    acc.z = fmaf(av, wv4.z, acc.z);
    acc.w = fmaf(av, wv4.w, acc.w);
  }
  *(float4*)(o + i*HH + 4*fq) = acc;
}

// ---------------------------------------------------------------- agg1 + relu + gemm2 fused
// h1 row lives in registers (one float/lane); gemm2 via 64 shfl broadcasts,
// ascending-k fmaf order -> bit-identical xw2.
__global__ __launch_bounds__(256) void agg_gemm2_kernel(const float* __restrict__ xw,
                                                        const int* __restrict__ nbr,
                                                        const float* __restrict__ ew,
                                                        const float* __restrict__ dis,
                                                        const float* __restrict__ b,
                                                        const int* __restrict__ sid,
                                                        const float* __restrict__ w2,
                                                        float* __restrict__ xw2) {
  int wv = threadIdx.x >> 6, lane = threadIdx.x & 63;
  int i = sid[(blockIdx.x << 2) + wv];
  float di = dis[i];
  float acc = 0.0f;
#pragma unroll 4
  for (int k = 0; k < KK; ++k) {
    int s = nbr[i*KK + k];
    float coef = (dis[s] * ew[i*KK + k]) * di;   // (dis[s]*w)*dis[t]
    acc = fmaf(coef, xw[s*HH + lane], acc);
  }
  acc = fmaf(di * di, xw[i*HH + lane], acc);     // self loop last
  float hv = fmaxf(acc + b[lane], 0.0f);         // h1[i][lane]
  float acc2 = 0.0f;
#pragma unroll 16
  for (int k = 0; k < HH; ++k) {
    float hk = __shfl(hv, k, 64);
    acc2 = fmaf(hk, w2[k*HH + lane], acc2);
  }
  xw2[i*HH + lane] = acc2;
}

// ---------------------------------------------------------------- agg2 + relu + fc (final)
__global__ __launch_bounds__(256) void agg_fc_kernel(const float* __restrict__ xw,
                                                     const int* __restrict__ nbr,
                                                     const float* __restrict__ ew,
                                                     const float* __restrict__ dis,
                                                     const float* __restrict__ b,
                                                     const float* __restrict__ wfc,
                                                     const float* __restrict__ bfc,
                                                     const int* __restrict__ sid,
                                                     float* __restrict__ out) {
  int wv = threadIdx.x >> 6, lane = threadIdx.x & 63;
  int i = sid[(blockIdx.x << 2) + wv];
  float di = dis[i];
  float acc = 0.0f;
#pragma unroll 4
  for (int k = 0; k < KK; ++k) {
    int s = nbr[i*KK + k];
    float coef = (dis[s] * ew[i*KK + k]) * di;
    acc = fmaf(coef, xw[s*HH + lane], acc);
  }
  acc = fmaf(di * di, xw[i*HH + lane], acc);
  float v = fmaxf(acc + b[lane], 0.0f);             // h2 feature
  float p = v * wfc[lane];                          // h2 @ Wfc  (F_OUT = 1)
#pragma unroll
  for (int off = 32; off > 0; off >>= 1) p = p + __shfl_xor(p, off, 64);
  if (lane == 0) out[i] = p + bfc[0];
}

// ---------------------------------------------------------------- launch
extern "C" void kernel_launch(void* const* d_in, const int* in_sizes, int n_in,
                              void* d_out, int out_size, void* d_ws, size_t ws_size,
                              hipStream_t stream) {
  (void)in_sizes; (void)n_in; (void)out_size; (void)ws_size;
  const float* x   = (const float*)d_in[0];
  const float* c   = (const float*)d_in[1];
  const float* W1  = (const float*)d_in[2];
  const float* b1  = (const float*)d_in[3];
  const float* W2  = (const float*)d_in[4];
  const float* b2  = (const float*)d_in[5];
  const float* Wfc = (const float*)d_in[6];
  const float* bfc = (const float*)d_in[7];
  float* out = (float*)d_out;

  char* ws = (char*)d_ws;
  size_t off = 0;
  auto alloc = [&](size_t bytes) -> void* {
    void* p = ws + off;
    off += (bytes + 255) & ~size_t(255);
    return p;
  };
  float4*   pack   = (float4*)  alloc(NN * sizeof(float4));       // 256 KB
  float4*   sorted = (float4*)  alloc(NN * sizeof(float4));       // 256 KB
  unsigned* cnt    = (unsigned*)alloc(NCELL * sizeof(unsigned));  // 16 KB
  unsigned* cstart = (unsigned*)alloc((NCELL+1) * sizeof(unsigned));
  unsigned* cursor = (unsigned*)alloc(NCELL * sizeof(unsigned));
  unsigned* cellid = (unsigned*)alloc(NN * sizeof(unsigned));     // 64 KB
  int*      sid    = (int*)     alloc(NN * sizeof(int));          // 64 KB
  int*      nbr    = (int*)     alloc(NE * sizeof(int));          // 1 MB
  float*    ew     = (float*)   alloc(NE * sizeof(float));        // 1 MB (d then ew in-place)
  float*    dis    = (float*)   alloc(NN * sizeof(float));        // 64 KB
  unsigned* gmm    = (unsigned*)alloc(2 * sizeof(unsigned));
  float*    xw1    = (float*)   alloc(NN * HH * sizeof(float));   // 4 MB
  float*    xw2    = (float*)   alloc(NN * HH * sizeof(float));   // 4 MB

  const int NB = (NN + 255) / 256;
  hipMemsetAsync(cnt, 0, NCELL * sizeof(unsigned), stream);
  prep_count_kernel<<<NB,   256, 0, stream>>>(c, pack, cellid, cnt, gmm);
  scan_kernel      <<<1,   1024, 0, stream>>>(cnt, cstart, cursor);
  scatter_kernel   <<<NB,   256, 0, stream>>>(pack, cellid, cursor, sorted, sid);
  gemm1_kernel     <<<NN*16/256, 256, 0, stream>>>(x, W1, xw1);
  knn_kernel       <<<NN/4, 256, 0, stream>>>(sorted, cstart, c, nbr, ew, gmm);
  ewdeg_kernel     <<<NB,   256, 0, stream>>>(gmm, ew, dis);
  agg_gemm2_kernel <<<NN/4, 256, 0, stream>>>(xw1, nbr, ew, dis, b1, sid, W2, xw2);
  agg_fc_kernel    <<<NN/4, 256, 0, stream>>>(xw2, nbr, ew, dis, b2, Wfc, bfc, sid, out);
}

// Round 10
// 156.786 us; speedup vs baseline: 3.1564x; 3.1564x over previous
//
#include <hip/hip_runtime.h>
#include <cstdint>

#define NN 16000
#define KK 16
#define FIN 32
#define HH 64
#define NE (NN*KK)
#define GG 64
#define NCELL (GG*GG)

// ---------------------------------------------------------------- prep + count
__global__ __launch_bounds__(256) void prep_count_kernel(const float* __restrict__ c,
                                                         float4* __restrict__ pack,
                                                         unsigned* __restrict__ cellid,
                                                         unsigned* __restrict__ cnt,
                                                         unsigned* __restrict__ gmm) {
#pragma clang fp contract(off)
  int i = blockIdx.x * 256 + threadIdx.x;
  if (i == 0) { gmm[0] = 0x7F800000u; gmm[1] = 0u; }  // min=+inf bits, max=0 (d>=0)
  if (i >= NN) return;
  float xv = c[2*i], yv = c[2*i+1];
  float xx = xv * xv;            // round(x^2)  (no fma: contract off)
  float yy = yv * yv;            // round(y^2)
  float sq = xx + yy;            // round(xx+yy)
  pack[i] = make_float4(xv, yv, sq, __uint_as_float((unsigned)i));
  int cx = (int)(xv * GG); cx = cx > GG-1 ? GG-1 : (cx < 0 ? 0 : cx);
  int cy = (int)(yv * GG); cy = cy > GG-1 ? GG-1 : (cy < 0 ? 0 : cy);
  unsigned cell = (unsigned)(cy * GG + cx);
  cellid[i] = cell;
  atomicAdd(&cnt[cell], 1u);
}

// ---------------------------------------------------------------- prefix scan (single block, wave-shuffle)
__global__ __launch_bounds__(1024) void scan_kernel(const unsigned* __restrict__ cnt,
                                                    unsigned* __restrict__ cstart,
                                                    unsigned* __restrict__ cursor) {
  __shared__ unsigned wsum[16];
  int tid = threadIdx.x;
  int lane = tid & 63, wv = tid >> 6;
  unsigned c0 = cnt[tid*4+0], c1 = cnt[tid*4+1], c2 = cnt[tid*4+2], c3 = cnt[tid*4+3];
  unsigned s = c0 + c1 + c2 + c3;
  unsigned v = s;
#pragma unroll
  for (int off = 1; off < 64; off <<= 1) {
    unsigned u = __shfl_up(v, off, 64);
    if (lane >= off) v += u;
  }
  if (lane == 63) wsum[wv] = v;
  __syncthreads();
  if (wv == 0) {
    unsigned t = (lane < 16) ? wsum[lane] : 0u;
    unsigned vv = t;
#pragma unroll
    for (int off = 1; off < 16; off <<= 1) {
      unsigned u = __shfl_up(vv, off, 64);
      if (lane >= off) vv += u;
    }
    if (lane < 16) wsum[lane] = vv - t;            // exclusive
  }
  __syncthreads();
  unsigned b = wsum[wv] + v - s;
  cstart[tid*4+0] = b; cursor[tid*4+0] = b; b += c0;
  cstart[tid*4+1] = b; cursor[tid*4+1] = b; b += c1;
  cstart[tid*4+2] = b; cursor[tid*4+2] = b; b += c2;
  cstart[tid*4+3] = b; cursor[tid*4+3] = b; b += c3;
  if (tid == 1023) cstart[NCELL] = b;              // == NN
}

// ---------------------------------------------------------------- scatter into cell order
__global__ __launch_bounds__(256) void scatter_kernel(const float4* __restrict__ pack,
                                                      const unsigned* __restrict__ cellid,
                                                      unsigned* __restrict__ cursor,
                                                      float4* __restrict__ sorted,
                                                      int* __restrict__ sid) {
  int i = blockIdx.x * 256 + threadIdx.x;
  if (i >= NN) return;
  unsigned p = atomicAdd(&cursor[cellid[i]], 1u);
  sorted[p] = pack[i];                             // .w carries original index bits
  sid[p] = i;
}

// ---------------------------------------------------------------- knn: 4 lanes/node (16 nodes/wave), pipelined
// d2 bit-exact vs passing rounds: dot = fma(y_i,y_j, round(x_i*x_j));
// d2 = round((sq_i+sq_j) - 2*dot). Key = map(d2bits)<<32 | j (index tie-break).
// Candidate loads are software-pipelined (next load issued before the insert
// chain consumes the current one). Stop test (hardware-validated in R9, exact):
// count of scanned keys with high32 <= map(edge^2 - 1e-5) over the quad >= 16.
// Merge: 16-round quad-min extraction. Edge epilogue identical ops to passing
// rounds; per-wave min/max butterfly + one atomic pair.
__global__ __launch_bounds__(256) void knn_kernel(const float4* __restrict__ sorted,
                                                  const unsigned* __restrict__ cstart,
                                                  const float* __restrict__ c,
                                                  int* __restrict__ nbr,
                                                  float* __restrict__ de,
                                                  unsigned* __restrict__ gmm) {
#pragma clang fp contract(off)
  const int g = blockIdx.x * 256 + threadIdx.x;
  const int t = g >> 2;                            // sorted node index
  const int q = g & 3;                             // quad lane
  const int lane = threadIdx.x & 63;
  const float4 me = sorted[t];
  const int myid = (int)__float_as_uint(me.w);
  const float h = 1.0f / GG;                       // exact 2^-6
  int cx = (int)(me.x * GG); cx = cx > GG-1 ? GG-1 : (cx < 0 ? 0 : cx);
  int cy = (int)(me.y * GG); cy = cy > GG-1 ? GG-1 : (cy < 0 ? 0 : cy);

  unsigned long long kd[KK];
#pragma unroll
  for (int m = 0; m < KK; ++m) kd[m] = ~0ull;

  auto process = [&](float4 cand) {
    int j = (int)__float_as_uint(cand.w);
    float xprod = me.x * cand.x;                       // round(x_i*x_j)
    float dot   = __builtin_fmaf(me.y, cand.y, xprod); // BLAS K=2 fma
    float S     = me.z + cand.z;                       // round(sq_i+sq_j)
    float twod  = dot + dot;                           // exact *2
    float d2    = S - twod;                            // one rounding
    unsigned ub = __float_as_uint(d2);
    ub = (ub & 0x80000000u) ? ~ub : (ub | 0x80000000u);
    unsigned long long key = ((unsigned long long)ub << 32) | (unsigned)j;
    if (j != myid && key < kd[KK-1]) {
      unsigned long long ck = key;
#pragma unroll
      for (int m = 0; m < KK; ++m) {
        bool sw = ck < kd[m];
        unsigned long long lo = sw ? ck : kd[m];
        unsigned long long hi = sw ? kd[m] : ck;
        kd[m] = lo; ck = hi;
      }
    }
  };
  // software-pipelined span scan: next load in flight while inserting current
  auto scanSpan = [&](unsigned p0, unsigned p1) {
    unsigned pp = p0 + (unsigned)q;
    if (pp >= p1) return;
    float4 cur = sorted[pp];
    unsigned pn = pp + 4;
    while (pn < p1) {
      float4 nxt = sorted[pn];
      process(cur);
      cur = nxt;
      pn += 4;
    }
    process(cur);
  };
  auto scanRow = [&](int y, int x0, int x1) {      // x0,x1 pre-clamped by caller
    unsigned p0 = cstart[y*GG + x0];
    unsigned p1 = cstart[y*GG + x1 + 1];
    scanSpan(p0, p1);
  };

  // ---- initial 5x5 rect: prefetch all row bounds, then scan
  int lxa = cx-2 < 0 ? 0 : cx-2;
  int lxb = cx+2 > GG-1 ? GG-1 : cx+2;
  int lya = cy-2 < 0 ? 0 : cy-2;
  int lyb = cy+2 > GG-1 ? GG-1 : cy+2;
  {
    unsigned rb0[5], rb1[5];
    int nr = lyb - lya + 1;
#pragma unroll
    for (int k = 0; k < 5; ++k) {
      int y = lya + k;
      if (k < nr) {
        rb0[k] = cstart[y*GG + lxa];
        rb1[k] = cstart[y*GG + lxb + 1];
      }
    }
#pragma unroll
    for (int k = 0; k < 5; ++k)
      if (k < nr) scanSpan(rb0[k], rb1[k]);
  }

  // ---- ring expansion with exact count-based stop (validated R9)
  int R = 2;
  while (true) {
    bool whole = (lxa <= 0) && (lxb >= GG-1) && (lya <= 0) && (lyb >= GG-1);
    bool done = whole;
    if (!done) {
      float edge = 1e30f;
      if (lxa > 0)    edge = fminf(edge, me.x - (float)lxa * h);
      if (lxb < GG-1) edge = fminf(edge, (float)(lxb+1) * h - me.x);
      if (lya > 0)    edge = fminf(edge, me.y - (float)lya * h);
      if (lyb < GG-1) edge = fminf(edge, (float)(lyb+1) * h - me.y);
      float lim = edge * edge - 1e-5f;             // margin >> Gram noise (~1e-6)
      if (lim > 0.0f) {
        unsigned lb = __float_as_uint(lim) | 0x80000000u;   // map(lim), lim>0
        int cle = 0;
#pragma unroll
        for (int m = 0; m < KK; ++m) cle += ((unsigned)(kd[m] >> 32) <= lb) ? 1 : 0;
        cle += __shfl_xor(cle, 1, 64);
        cle += __shfl_xor(cle, 2, 64);
        done = cle >= KK;
      }
    }
    if (done) break;
    ++R;
    int nxa = cx-R < 0 ? 0 : cx-R;
    int nxb = cx+R > GG-1 ? GG-1 : cx+R;
    int nya = cy-R < 0 ? 0 : cy-R;
    int nyb = cy+R > GG-1 ? GG-1 : cy+R;
    if (nya < lya) scanRow(nya, nxa, nxb);
    if (nyb > lyb) scanRow(nyb, nxa, nxb);
    if (nxa < lxa) for (int y = lya; y <= lyb; ++y) scanRow(y, nxa, nxa);
    if (nxb > lxb) for (int y = lya; y <= lyb; ++y) scanRow(y, nxb, nxb);
    lxa = nxa; lxb = nxb; lya = nya; lyb = nyb;
  }

  // ---- merge 4 sorted per-lane lists -> global top-16 (keys unique via j bits)
  unsigned res[4];
  for (int r = 0; r < KK; ++r) {
    unsigned long long md = kd[0];
    unsigned long long m1 = __shfl_xor(md, 1, 64); md = m1 < md ? m1 : md;
    unsigned long long m2 = __shfl_xor(md, 2, 64); md = m2 < md ? m2 : md;
    if (kd[0] == md) {                              // unique winner lane pops
#pragma unroll
      for (int m = 0; m < KK-1; ++m) kd[m] = kd[m+1];
      kd[KK-1] = ~0ull;
    }
    if ((r >> 2) == q) res[r & 3] = (unsigned)(md & 0xFFFFFFFFull);
  }

  // ---- write nbr + edge epilogue (identical ops to passing rounds)
  int4 w4; w4.x = (int)res[0]; w4.y = (int)res[1]; w4.z = (int)res[2]; w4.w = (int)res[3];
  *(int4*)(nbr + myid*KK + 4*q) = w4;
  unsigned bmin = 0xFFFFFFFFu, bmax = 0u;
#pragma unroll
  for (int e = 0; e < 4; ++e) {
    int j = (int)res[e];
    float dx = me.x - c[2*j];
    float dy = me.y - c[2*j+1];
    float xx = dx * dx;
    float yy = dy * dy;
    float d  = __builtin_sqrtf(xx + yy);
    de[myid*KK + 4*q + e] = d;
    unsigned bb = __float_as_uint(d);               // d >= 0: bit order == float order
    bmin = bmin < bb ? bmin : bb;
    bmax = bmax > bb ? bmax : bb;
  }
#pragma unroll
  for (int off = 32; off > 0; off >>= 1) {
    unsigned ob = __shfl_xor(bmin, off, 64);
    bmin = bmin < ob ? bmin : ob;
    unsigned oB = __shfl_xor(bmax, off, 64);
    bmax = bmax > oB ? bmax : oB;
  }
  if (lane == 0) {
    atomicMin(&gmm[0], bmin);
    atomicMax(&gmm[1], bmax);
  }
}

// ---------------------------------------------------------------- ew + deg + dis
__global__ __launch_bounds__(256) void ewdeg_kernel(const unsigned* __restrict__ gmm,
                                                    float* __restrict__ de,   // in: d, out: ew
                                                    float* __restrict__ dis) {
#pragma clang fp contract(off)
  int i = blockIdx.x * 256 + threadIdx.x;
  if (i >= NN) return;
  float mx  = __uint_as_float(gmm[1]);
  float rng = mx - __uint_as_float(gmm[0]);
  float deg = 0.0f;                         // edges first, self-loop last (segment_sum order)
  float4* dp = (float4*)(de + i*KK);
#pragma unroll
  for (int qq = 0; qq < 4; ++qq) {
    float4 v = dp[qq];
    float e0 = (mx - v.x) / rng;
    float e1 = (mx - v.y) / rng;
    float e2 = (mx - v.z) / rng;
    float e3 = (mx - v.w) / rng;
    deg = deg + e0; deg = deg + e1;
    deg = deg + e2; deg = deg + e3;
    dp[qq] = make_float4(e0, e1, e2, e3);
  }
  deg = deg + 1.0f;                         // self-loop weight 1, added last
  dis[i] = 1.0f / __builtin_sqrtf(deg);     // deg >= 1
}

// ---------------------------------------------------------------- gemm1: xw1 = x @ W1, KIN=32, 4 features/thread
__global__ __launch_bounds__(256) void gemm1_kernel(const float* __restrict__ a,
                                                    const float* __restrict__ w,
                                                    float* __restrict__ o) {
  int gid = blockIdx.x * 256 + threadIdx.x;   // N*16 total
  int i = gid >> 4, fq = gid & 15;
  const float4* ar = (const float4*)(a + i * FIN);
  float4 A[FIN/4];
#pragma unroll
  for (int qq = 0; qq < FIN/4; ++qq) A[qq] = ar[qq];
  float4 acc = make_float4(0.f, 0.f, 0.f, 0.f);
#pragma unroll
  for (int k = 0; k < FIN; ++k) {
    float av = ((const float*)A)[k];
    float4 wv4 = *(const float4*)(w + k*HH + 4*fq);
    acc.x = fmaf(av, wv4.x, acc.x);
    acc.y = fmaf(av, wv4.y, acc.y);
    acc.z = fmaf(av, wv4.z, acc.z);
    acc.w = fmaf(av, wv4.w, acc.w);
  }
  *(float4*)(o + i*HH + 4*fq) = acc;
}

// ---------------------------------------------------------------- agg1 + relu + gemm2 fused
// h1 row lives in registers (one float/lane); gemm2 via 64 shfl broadcasts,
// ascending-k fmaf order -> bit-identical xw2.
__global__ __launch_bounds__(256) void agg_gemm2_kernel(const float* __restrict__ xw,
                                                        const int* __restrict__ nbr,
                                                        const float* __restrict__ ew,
                                                        const float* __restrict__ dis,
                                                        const float* __restrict__ b,
                                                        const int* __restrict__ sid,
                                                        const float* __restrict__ w2,
                                                        float* __restrict__ xw2) {
  int wv = threadIdx.x >> 6, lane = threadIdx.x & 63;
  int i = sid[(blockIdx.x << 2) + wv];
  float di = dis[i];
  float acc = 0.0f;
#pragma unroll 4
  for (int k = 0; k < KK; ++k) {
    int s = nbr[i*KK + k];
    float coef = (dis[s] * ew[i*KK + k]) * di;   // (dis[s]*w)*dis[t]
    acc = fmaf(coef, xw[s*HH + lane], acc);
  }
  acc = fmaf(di * di, xw[i*HH + lane], acc);     // self loop last
  float hv = fmaxf(acc + b[lane], 0.0f);         // h1[i][lane]
  float acc2 = 0.0f;
#pragma unroll 16
  for (int k = 0; k < HH; ++k) {
    float hk = __shfl(hv, k, 64);
    acc2 = fmaf(hk, w2[k*HH + lane], acc2);
  }
  xw2[i*HH + lane] = acc2;
}

// ---------------------------------------------------------------- agg2 + relu + fc (final)
__global__ __launch_bounds__(256) void agg_fc_kernel(const float* __restrict__ xw,
                                                     const int* __restrict__ nbr,
                                                     const float* __restrict__ ew,
                                                     const float* __restrict__ dis,
                                                     const float* __restrict__ b,
                                                     const float* __restrict__ wfc,
                                                     const float* __restrict__ bfc,
                                                     const int* __restrict__ sid,
                                                     float* __restrict__ out) {
  int wv = threadIdx.x >> 6, lane = threadIdx.x & 63;
  int i = sid[(blockIdx.x << 2) + wv];
  float di = dis[i];
  float acc = 0.0f;
#pragma unroll 4
  for (int k = 0; k < KK; ++k) {
    int s = nbr[i*KK + k];
    float coef = (dis[s] * ew[i*KK + k]) * di;
    acc = fmaf(coef, xw[s*HH + lane], acc);
  }
  acc = fmaf(di * di, xw[i*HH + lane], acc);
  float v = fmaxf(acc + b[lane], 0.0f);             // h2 feature
  float p = v * wfc[lane];                          // h2 @ Wfc  (F_OUT = 1)
#pragma unroll
  for (int off = 32; off > 0; off >>= 1) p = p + __shfl_xor(p, off, 64);
  if (lane == 0) out[i] = p + bfc[0];
}

// ---------------------------------------------------------------- launch
extern "C" void kernel_launch(void* const* d_in, const int* in_sizes, int n_in,
                              void* d_out, int out_size, void* d_ws, size_t ws_size,
                              hipStream_t stream) {
  (void)in_sizes; (void)n_in; (void)out_size; (void)ws_size;
  const float* x   = (const float*)d_in[0];
  const float* c   = (const float*)d_in[1];
  const float* W1  = (const float*)d_in[2];
  const float* b1  = (const float*)d_in[3];
  const float* W2  = (const float*)d_in[4];
  const float* b2  = (const float*)d_in[5];
  const float* Wfc = (const float*)d_in[6];
  const float* bfc = (const float*)d_in[7];
  float* out = (float*)d_out;

  char* ws = (char*)d_ws;
  size_t off = 0;
  auto alloc = [&](size_t bytes) -> void* {
    void* p = ws + off;
    off += (bytes + 255) & ~size_t(255);
    return p;
  };
  float4*   pack   = (float4*)  alloc(NN * sizeof(float4));       // 256 KB
  float4*   sorted = (float4*)  alloc(NN * sizeof(float4));       // 256 KB
  unsigned* cnt    = (unsigned*)alloc(NCELL * sizeof(unsigned));  // 16 KB
  unsigned* cstart = (unsigned*)alloc((NCELL+1) * sizeof(unsigned));
  unsigned* cursor = (unsigned*)alloc(NCELL * sizeof(unsigned));
  unsigned* cellid = (unsigned*)alloc(NN * sizeof(unsigned));     // 64 KB
  int*      sid    = (int*)     alloc(NN * sizeof(int));          // 64 KB
  int*      nbr    = (int*)     alloc(NE * sizeof(int));          // 1 MB
  float*    ew     = (float*)   alloc(NE * sizeof(float));        // 1 MB (d then ew in-place)
  float*    dis    = (float*)   alloc(NN * sizeof(float));        // 64 KB
  unsigned* gmm    = (unsigned*)alloc(2 * sizeof(unsigned));
  float*    xw1    = (float*)   alloc(NN * HH * sizeof(float));   // 4 MB
  float*    xw2    = (float*)   alloc(NN * HH * sizeof(float));   // 4 MB

  const int NB = (NN + 255) / 256;
  hipMemsetAsync(cnt, 0, NCELL * sizeof(unsigned), stream);
  prep_count_kernel<<<NB,   256, 0, stream>>>(c, pack, cellid, cnt, gmm);
  scan_kernel      <<<1,   1024, 0, stream>>>(cnt, cstart, cursor);
  scatter_kernel   <<<NB,   256, 0, stream>>>(pack, cellid, cursor, sorted, sid);
  gemm1_kernel     <<<NN*16/256, 256, 0, stream>>>(x, W1, xw1);
  knn_kernel       <<<NN*4/256,  256, 0, stream>>>(sorted, cstart, c, nbr, ew, gmm);
  ewdeg_kernel     <<<NB,   256, 0, stream>>>(gmm, ew, dis);
  agg_gemm2_kernel <<<NN/4, 256, 0, stream>>>(xw1, nbr, ew, dis, b1, sid, W2, xw2);
  agg_fc_kernel    <<<NN/4, 256, 0, stream>>>(xw2, nbr, ew, dis, b2, Wfc, bfc, sid, out);
}